// Round 5
// baseline (222.452 us; speedup 1.0000x reference)
//
#include <hip/hip_runtime.h>
#include <hip/hip_bf16.h>

// VectorQuantizer via MFMA: scores = en2 - 2*Z.E^T as bf16 hi/lo 3-product MFMA
// (approx, error <= ~2e-5), then exact fp32 rescore (reference-replicated
// arithmetic, validated absmax 0.0 in R1-R4) of all codes within EPS of the
// row min. Tie-break = u64 (dist_bits<<32 | idx) atomicMin == strict-< ascending-k.
constexpr int NELEM = 8388608;            // 32*64*64*64
constexpr int ROWS  = 64;                 // rows per block
constexpr int NBLK  = 131072 / ROWS;      // 2048
constexpr int SS    = 516;                // score tile stride (dwords)
constexpr int ZS    = 68;                 // z tile stride (dwords)
constexpr float EPS = 2e-4f;              // >= 2*(approx err + ref rounding), ~4x margin

typedef short bf16x8 __attribute__((ext_vector_type(8)));
typedef float v4f    __attribute__((ext_vector_type(4)));

// 8 consecutive fp32 -> bf16 hi + bf16 lo (lo = rne(x - hi)), optional scale.
__device__ inline void cvt_hilo8(const float* __restrict__ s, float scale,
                                 bf16x8& hi, bf16x8& lo) {
#pragma unroll
    for (int j = 0; j < 8; ++j) {
        float x = scale * s[j];
        __hip_bfloat16 h = __float2bfloat16(x);
        float hf = __bfloat162float(h);
        __hip_bfloat16 l = __float2bfloat16(x - hf);
        hi[j] = (short)__bfloat16_as_ushort(h);
        lo[j] = (short)__bfloat16_as_ushort(l);
    }
}

// Block = 512 threads = 8 waves; 64 z-rows, all 512 codes.
// Wave w owns code-tiles [4w, 4w+4) (64 codes) x all 64 rows (4 row-tiles).
// MFMA 16x16x32: A = (-2*E) codes (m=lane&15, k=quad*8+j), B = Z rows
// (n=lane&15), C: col=lane&15 (z-row), row=quad*4+reg (code) [m89 layout].
__global__ __launch_bounds__(512) __attribute__((amdgpu_waves_per_eu(2, 2)))
void vq_main(const float* __restrict__ z,
             const float* __restrict__ emb,
             float* __restrict__ out) {
    __shared__ float s_scores[ROWS * SS];      // 129 KB: [row][code(+pad)]
    __shared__ float s_z[ROWS * ZS];           // 17.4 KB fp32 z tile (padded)
    __shared__ float s_en2[512];
    __shared__ float s_pmin[512];
    __shared__ float s_rowmin[ROWS];
    __shared__ float s_zn2[ROWS];
    __shared__ unsigned long long s_key[ROWS];
    __shared__ float s_lpart[8];

    const int tid  = threadIdx.x;
    const int lane = tid & 63;
    const int wid  = tid >> 6;
    const int mcol = lane & 15;
    const int quad = lane >> 4;

    // ---- z tile -> LDS (coalesced, 8 floats/thread) ----
    {
        const int row = tid >> 3, seg = tid & 7;
        const float4* gp = (const float4*)(z + ((size_t)blockIdx.x * ROWS + row) * 64 + seg * 8);
        float4 v0 = gp[0], v1 = gp[1];
        *(float4*)&s_z[row * ZS + seg * 8]     = v0;
        *(float4*)&s_z[row * ZS + seg * 8 + 4] = v1;
    }
    // ---- exact en2 (reference quad-accumulator order) ----
    {
        const float4* e4 = (const float4*)(emb + (size_t)tid * 64);
        float a = 0.f, b = 0.f, c = 0.f, d = 0.f;
#pragma unroll
        for (int i = 0; i < 16; ++i) {
            float4 v = e4[i];
            a += v.x * v.x; b += v.y * v.y; c += v.z * v.z; d += v.w * v.w;
        }
        s_en2[tid] = (a + b) + (c + d);
    }
    if (tid < ROWS) s_key[tid] = ~0ULL;
    __syncthreads();

    // ---- exact zn2 per row (reference order) ----
    if (tid < ROWS) {
        const float* zr = &s_z[tid * ZS];
        float a = 0.f, b = 0.f, c = 0.f, d = 0.f;
#pragma unroll
        for (int i = 0; i < 16; ++i) {
            a += zr[4*i]   * zr[4*i];   b += zr[4*i+1] * zr[4*i+1];
            c += zr[4*i+2] * zr[4*i+2]; d += zr[4*i+3] * zr[4*i+3];
        }
        s_zn2[tid] = (a + b) + (c + d);
    }

    // ---- build fragments: Z (hi/lo) for 4 row-tiles, -2E (hi/lo) for wave's 4 code-tiles ----
    bf16x8 zH[4][2], zL[4][2], eH[4][2], eL[4][2];
#pragma unroll
    for (int rt = 0; rt < 4; ++rt)
#pragma unroll
        for (int kc = 0; kc < 2; ++kc)
            cvt_hilo8(&s_z[(rt * 16 + mcol) * ZS + kc * 32 + quad * 8], 1.0f,
                      zH[rt][kc], zL[rt][kc]);
#pragma unroll
    for (int ct = 0; ct < 4; ++ct)
#pragma unroll
        for (int kc = 0; kc < 2; ++kc)
            cvt_hilo8(emb + (size_t)((wid * 4 + ct) * 16 + mcol) * 64 + kc * 32 + quad * 8,
                      -2.0f, eH[ct][kc], eL[ct][kc]);

    // ---- MFMA: acc init = en2[code]; 6 MFMAs per (ct,rt); write scores ----
#pragma unroll
    for (int ct = 0; ct < 4; ++ct) {
        const int gct = wid * 4 + ct;
        const float* e2p = &s_en2[gct * 16 + quad * 4];
        v4f ai = { e2p[0], e2p[1], e2p[2], e2p[3] };
        v4f acc[4];
#pragma unroll
        for (int rt = 0; rt < 4; ++rt) acc[rt] = ai;
#pragma unroll
        for (int kc = 0; kc < 2; ++kc) {
#pragma unroll
            for (int rt = 0; rt < 4; ++rt)
                acc[rt] = __builtin_amdgcn_mfma_f32_16x16x32_bf16(eH[ct][kc], zH[rt][kc], acc[rt], 0, 0, 0);
#pragma unroll
            for (int rt = 0; rt < 4; ++rt)
                acc[rt] = __builtin_amdgcn_mfma_f32_16x16x32_bf16(eH[ct][kc], zL[rt][kc], acc[rt], 0, 0, 0);
#pragma unroll
            for (int rt = 0; rt < 4; ++rt)
                acc[rt] = __builtin_amdgcn_mfma_f32_16x16x32_bf16(eL[ct][kc], zH[rt][kc], acc[rt], 0, 0, 0);
        }
#pragma unroll
        for (int rt = 0; rt < 4; ++rt)
            *(v4f*)&s_scores[(rt * 16 + mcol) * SS + gct * 16 + quad * 4] = acc[rt];
    }
    __syncthreads();

    // ---- scan: row min over approx scores (8 threads/row x 64 codes) ----
    const int srow = tid >> 3, sseg = tid & 7;
    const float* sp = &s_scores[srow * SS + sseg * 64];
    {
        float mn = 3.402823466e38f;
#pragma unroll
        for (int i = 0; i < 16; ++i) {
            v4f v = *(const v4f*)(sp + i * 4);
            mn = fminf(mn, fminf(fminf(v.x, v.y), fminf(v.z, v.w)));
        }
        s_pmin[tid] = mn;
    }
    __syncthreads();
    if (tid < ROWS) {
        float m = s_pmin[tid * 8];
#pragma unroll
        for (int i = 1; i < 8; ++i) m = fminf(m, s_pmin[tid * 8 + i]);
        s_rowmin[tid] = m + EPS;
    }
    __syncthreads();

    // ---- candidates within EPS -> exact reference rescore -> u64 key atomicMin ----
    {
        const float thr = s_rowmin[srow];
        const float zn2 = s_zn2[srow];
        int cand[8]; int nc = 0;
        for (int i = 0; i < 16; ++i) {
            v4f v = *(const v4f*)(sp + i * 4);
#pragma unroll
            for (int j = 0; j < 4; ++j)
                if (v[j] <= thr && nc < 8) cand[nc++] = sseg * 64 + i * 4 + j;
        }
        const float* zr = &s_z[srow * ZS];
        for (int u = 0; u < nc; ++u) {
            const int c = cand[u];
            const float* er = emb + (size_t)c * 64;
            float a = 0.f, b = 0.f, c2 = 0.f, d = 0.f;
#pragma unroll
            for (int g = 0; g < 16; ++g) {
                a  += zr[4*g]   * er[4*g];   b += zr[4*g+1] * er[4*g+1];
                c2 += zr[4*g+2] * er[4*g+2]; d += zr[4*g+3] * er[4*g+3];
            }
            float dot  = (a + b) + (c2 + d);
            float dist = (zn2 + s_en2[c]) - 2.0f * dot;   // reference expression
            unsigned long long key =
                ((unsigned long long)__float_as_uint(dist) << 32) | (unsigned)c;
            atomicMin(&s_key[srow], key);
        }
    }
    __syncthreads();

    // ---- epilogue: quantized_st, indices, loss ----
    const int widx = (int)(unsigned)(s_key[srow] & 0x1FFULL);
    const float* er = emb + (size_t)widx * 64 + sseg * 8;
    const float* zr = &s_z[srow * ZS + sseg * 8];
    float* qo = out + 1 + ((size_t)blockIdx.x * ROWS + srow) * 64 + sseg * 8;
    float lsum = 0.f;
#pragma unroll
    for (int j = 0; j < 8; ++j) {
        float zv = zr[j], ev = er[j];
        float q = zv + (ev - zv);    // reference STE arithmetic
        float df = q - zv; lsum += df * df;
        qo[j] = q;
    }
    if (sseg == 0)
        out[1 + NELEM + blockIdx.x * ROWS + srow] = (float)widx;

#pragma unroll
    for (int off = 32; off; off >>= 1) lsum += __shfl_down(lsum, off, 64);
    if (lane == 0) s_lpart[wid] = lsum;
    __syncthreads();
    if (tid == 0) {
        float p = 0.f;
#pragma unroll
        for (int w = 0; w < 8; ++w) p += s_lpart[w];
        atomicAdd(out, p * (1.25f / 8388608.0f));   // recon + 0.25*commit
    }
}

extern "C" void kernel_launch(void* const* d_in, const int* in_sizes, int n_in,
                              void* d_out, int out_size, void* d_ws, size_t ws_size,
                              hipStream_t stream) {
    const float* z   = (const float*)d_in[0];
    const float* emb = (const float*)d_in[1];
    float* out = (float*)d_out;

    hipMemsetAsync(out, 0, 4, stream);  // zero loss accumulator (capture-safe)
    vq_main<<<NBLK, 512, 0, stream>>>(z, emb, out);
}

// Round 6
// 170.852 us; speedup vs baseline: 1.3020x; 1.3020x over previous
//
#include <hip/hip_runtime.h>
#include <hip/hip_bf16.h>

// VectorQuantizer via MFMA, scores retained in registers (no LDS score tile).
// Numerics identical to R5 (absmax 0.0): scores = en2 - 2*Z.E^T via bf16 hi/lo
// 3-product MFMA (err <= ~1e-5), EPS=2e-4 band, exact fp32 reference rescore,
// u64 (dist_bits<<32|idx) atomicMin == strict-< ascending-k tie-break.
constexpr int NELEM = 8388608;            // 32*64*64*64
constexpr int ROWS  = 64;                 // rows per block
constexpr int NBLK  = 131072 / ROWS;      // 2048
constexpr int ZS    = 68;                 // z tile stride (dwords)
constexpr float EPS = 2e-4f;              // R5-validated band
constexpr int QCAP  = 1024;               // candidate queue capacity (~73 expected)

typedef short bf16x8 __attribute__((ext_vector_type(8)));
typedef float v4f    __attribute__((ext_vector_type(4)));

// Precomputed E fragments: [ct][kc][hi/lo][lane] -> 8 bf16 (16B), 128 KB total.
// Main loop loads g_efrag[ct][kc][p][lane] = coalesced 16B/lane dwordx4, L2-hot.
__device__ bf16x8 g_efrag[32][2][2][64];

// 8 consecutive fp32 -> bf16 hi + lo (lo = rne(x - hi)), scaled. Same as R5.
__device__ inline void cvt_hilo8(const float* __restrict__ s, float scale,
                                 bf16x8& hi, bf16x8& lo) {
#pragma unroll
    for (int j = 0; j < 8; ++j) {
        float x = scale * s[j];
        __hip_bfloat16 h = __float2bfloat16(x);
        float hf = __bfloat162float(h);
        __hip_bfloat16 l = __float2bfloat16(x - hf);
        hi[j] = (short)__bfloat16_as_ushort(h);
        lo[j] = (short)__bfloat16_as_ushort(l);
    }
}

// Build E fragments once: A-operand layout A[m=lane&15][k=quad*8+j], scale -2.
__global__ void __launch_bounds__(256) vq_prep(const float* __restrict__ emb) {
#pragma unroll
    for (int t = 0; t < 16; ++t) {
        const int id   = threadIdx.x + 256 * t;   // (ct,kc,lane) tuple, 4096 total
        const int lane = id & 63;
        const int kc   = (id >> 6) & 1;
        const int ct   = id >> 7;
        const float* src = emb + (size_t)(ct * 16 + (lane & 15)) * 64
                               + kc * 32 + (lane >> 4) * 8;
        bf16x8 hi, lo;
        cvt_hilo8(src, -2.0f, hi, lo);
        g_efrag[ct][kc][0][lane] = hi;
        g_efrag[ct][kc][1][lane] = lo;
    }
}

// Block = 256 threads = 4 waves, 64 rows. Wave w owns rows [16w,16w+16) x all
// 512 codes; per-lane scores for (row=mcol, code=ct*16+quad*4+reg) stay in
// acc[32] (128 VGPRs). MFMA 16x16x32: A=-2E (m=code), B=Z (n=row),
// C: col=lane&15 (row), row=quad*4+reg (code) [m89 layout, R5-validated].
__global__ __launch_bounds__(256) __attribute__((amdgpu_waves_per_eu(2, 2)))
void vq_main(const float* __restrict__ z,
             const float* __restrict__ emb,
             float* __restrict__ out) {
    __shared__ float s_z[ROWS * ZS];          // 17.4 KB fp32 z tile
    __shared__ float s_en2[512];
    __shared__ float s_zn2[ROWS];
    __shared__ unsigned long long s_key[ROWS];
    __shared__ unsigned s_q[QCAP];            // (row<<16)|code
    __shared__ int s_qn;
    __shared__ float s_lpart[4];

    const int tid  = threadIdx.x;
    const int lane = tid & 63;
    const int wid  = __builtin_amdgcn_readfirstlane(tid >> 6);
    const int mcol = lane & 15;
    const int quad = lane >> 4;

    // ---- stage z tile (coalesced), init queue/keys ----
    {
        const int row = tid >> 2, seg = tid & 3;
        const float4* gp = (const float4*)(z + ((size_t)blockIdx.x * ROWS + row) * 64 + seg * 16);
#pragma unroll
        for (int i = 0; i < 4; ++i)
            *(float4*)&s_z[row * ZS + seg * 16 + i * 4] = gp[i];
    }
    // ---- exact en2 (reference quad-accumulator order), 2 codes/thread ----
#pragma unroll
    for (int c = 0; c < 2; ++c) {
        const int k = tid + c * 256;
        const float4* e4 = (const float4*)(emb + (size_t)k * 64);
        float a = 0.f, b = 0.f, cc = 0.f, d = 0.f;
#pragma unroll
        for (int i = 0; i < 16; ++i) {
            float4 v = e4[i];
            a += v.x * v.x; b += v.y * v.y; cc += v.z * v.z; d += v.w * v.w;
        }
        s_en2[k] = (a + b) + (cc + d);
    }
    if (tid < ROWS) s_key[tid] = ~0ULL;
    if (tid == 0) s_qn = 0;
    __syncthreads();

    // ---- exact zn2 per row (reference order) ----
    if (tid < ROWS) {
        const float* zr = &s_z[tid * ZS];
        float a = 0.f, b = 0.f, c = 0.f, d = 0.f;
#pragma unroll
        for (int i = 0; i < 16; ++i) {
            a += zr[4*i]   * zr[4*i];   b += zr[4*i+1] * zr[4*i+1];
            c += zr[4*i+2] * zr[4*i+2]; d += zr[4*i+3] * zr[4*i+3];
        }
        s_zn2[tid] = (a + b) + (c + d);
    }

    // ---- Z fragments (hi/lo) for this wave's 16 rows ----
    const int zrow = wid * 16 + mcol;
    bf16x8 zH0, zL0, zH1, zL1;
    cvt_hilo8(&s_z[zrow * ZS +  0 + quad * 8], 1.0f, zH0, zL0);
    cvt_hilo8(&s_z[zrow * ZS + 32 + quad * 8], 1.0f, zH1, zL1);

    // ---- main loop: 32 code-tiles, scores retained in acc[] ----
    v4f acc[32];
    float lmin = 3.402823466e38f;
#pragma unroll
    for (int ct = 0; ct < 32; ++ct) {
        bf16x8 eH0 = g_efrag[ct][0][0][lane];
        bf16x8 eL0 = g_efrag[ct][0][1][lane];
        bf16x8 eH1 = g_efrag[ct][1][0][lane];
        bf16x8 eL1 = g_efrag[ct][1][1][lane];
        v4f a = *(const v4f*)&s_en2[ct * 16 + quad * 4];  // broadcast read
        a = __builtin_amdgcn_mfma_f32_16x16x32_bf16(eH0, zH0, a, 0, 0, 0);
        a = __builtin_amdgcn_mfma_f32_16x16x32_bf16(eH0, zL0, a, 0, 0, 0);
        a = __builtin_amdgcn_mfma_f32_16x16x32_bf16(eL0, zH0, a, 0, 0, 0);
        a = __builtin_amdgcn_mfma_f32_16x16x32_bf16(eH1, zH1, a, 0, 0, 0);
        a = __builtin_amdgcn_mfma_f32_16x16x32_bf16(eH1, zL1, a, 0, 0, 0);
        a = __builtin_amdgcn_mfma_f32_16x16x32_bf16(eL1, zH1, a, 0, 0, 0);
        acc[ct] = a;
        lmin = fminf(lmin, fminf(fminf(a.x, a.y), fminf(a.z, a.w)));
    }

    // ---- row min across quads (lanes mcol, mcol+16, +32, +48) ----
    lmin = fminf(lmin, __shfl_xor(lmin, 16, 64));
    lmin = fminf(lmin, __shfl_xor(lmin, 32, 64));
    const float thr = lmin + EPS;

    // ---- band scan over register scores -> candidate queue ----
#pragma unroll
    for (int ct = 0; ct < 32; ++ct) {
        v4f a = acc[ct];
        float m4 = fminf(fminf(a.x, a.y), fminf(a.z, a.w));
        if (m4 <= thr) {
#pragma unroll
            for (int r = 0; r < 4; ++r) {
                if (a[r] <= thr) {
                    int slot = atomicAdd(&s_qn, 1);
                    if (slot < QCAP)
                        s_q[slot] = ((unsigned)zrow << 16) | (unsigned)(ct * 16 + quad * 4 + r);
                }
            }
        }
    }
    __syncthreads();

    // ---- exact reference rescore of candidates (parallel pass) ----
    {
        const int qn = s_qn;
        for (int i = tid; i < qn && i < QCAP; i += 256) {
            const unsigned e = s_q[i];
            const int row = e >> 16, code = e & 0xFFFF;
            const float* zr = &s_z[row * ZS];
            const float* er = emb + (size_t)code * 64;
            float a = 0.f, b = 0.f, c2 = 0.f, d = 0.f;
#pragma unroll
            for (int g = 0; g < 16; ++g) {
                a  += zr[4*g]   * er[4*g];   b += zr[4*g+1] * er[4*g+1];
                c2 += zr[4*g+2] * er[4*g+2]; d += zr[4*g+3] * er[4*g+3];
            }
            float dot  = (a + b) + (c2 + d);
            float dist = (s_zn2[row] + s_en2[code]) - 2.0f * dot;  // reference expr
            unsigned long long key =
                ((unsigned long long)__float_as_uint(dist) << 32) | (unsigned)code;
            atomicMin(&s_key[row], key);
        }
    }
    __syncthreads();

    // ---- epilogue: quantized_st, indices, loss (row = tid>>2, 16 floats) ----
    const int row = tid >> 2, seg = tid & 3;
    const int widx = (int)(unsigned)(s_key[row] & 0x1FFULL);
    const float* er = emb + (size_t)widx * 64 + seg * 16;
    const float* zr = &s_z[row * ZS + seg * 16];
    float* qo = out + 1 + ((size_t)blockIdx.x * ROWS + row) * 64 + seg * 16;
    float lsum = 0.f;
#pragma unroll
    for (int j = 0; j < 16; ++j) {
        float zv = zr[j], ev = er[j];
        float q = zv + (ev - zv);    // reference STE arithmetic
        float df = q - zv; lsum += df * df;
        qo[j] = q;
    }
    if (seg == 0)
        out[1 + NELEM + blockIdx.x * ROWS + row] = (float)widx;

#pragma unroll
    for (int off = 32; off; off >>= 1) lsum += __shfl_down(lsum, off, 64);
    if (lane == 0) s_lpart[wid] = lsum;
    __syncthreads();
    if (tid == 0) {
        float p = (s_lpart[0] + s_lpart[1]) + (s_lpart[2] + s_lpart[3]);
        atomicAdd(out, p * (1.25f / 8388608.0f));   // recon + 0.25*commit
    }
}

extern "C" void kernel_launch(void* const* d_in, const int* in_sizes, int n_in,
                              void* d_out, int out_size, void* d_ws, size_t ws_size,
                              hipStream_t stream) {
    const float* z   = (const float*)d_in[0];
    const float* emb = (const float*)d_in[1];
    float* out = (float*)d_out;

    hipMemsetAsync(out, 0, 4, stream);  // zero loss accumulator (capture-safe)
    vq_prep<<<1, 256, 0, stream>>>(emb);
    vq_main<<<NBLK, 256, 0, stream>>>(z, emb, out);
}